// Round 11
// baseline (186.404 us; speedup 1.0000x reference)
//
#include <hip/hip_runtime.h>
#include <hip/hip_bf16.h>

#define L_SEQ 2048
#define DM 512

typedef short bf16x8 __attribute__((ext_vector_type(8)));
typedef float f32x4 __attribute__((ext_vector_type(4)));
typedef float f32x16 __attribute__((ext_vector_type(16)));
typedef unsigned short u16;
typedef u16 u16x8 __attribute__((ext_vector_type(8)));
typedef u16 u16x4 __attribute__((ext_vector_type(4)));
typedef unsigned int u32x2 __attribute__((ext_vector_type(2)));

__device__ __forceinline__ u16 f2bf(float f) {
    unsigned int u = __float_as_uint(f);
    u += 0x7fffu + ((u >> 16) & 1u);
    return (u16)(u >> 16);
}

__device__ __forceinline__ unsigned int pk_bf16(float a, float b) {
    __hip_bfloat162 h = __float22bfloat162_rn(float2{a, b});
    unsigned int u;
    __builtin_memcpy(&u, &h, 4);
    return u;
}

__device__ __forceinline__ void lds_load16(const void* g, void* l) {
    __builtin_amdgcn_global_load_lds(
        (const __attribute__((address_space(1))) unsigned int*)g,
        (__attribute__((address_space(3))) unsigned int*)l,
        16, 0, 0);
}

__device__ __forceinline__ f32x16 zero16() {
    f32x16 z;
#pragma unroll
    for (int i = 0; i < 16; ++i) z[i] = 0.f;
    return z;
}

// wide-period row swizzle: mixes ALL row bits into the 8-slot index (rows up to 128)
__device__ __forceinline__ int swz(int r) { return (r & 7) ^ ((r >> 3) & 7); }

// ---------------- prep: x transpose+cast (z<8) and weight casts (z==8) ----------------
__global__ void prep(const float* __restrict__ x1, const float* __restrict__ x2,
                     const float* __restrict__ Wq, const float* __restrict__ Wk,
                     const float* __restrict__ Wv,
                     u16* __restrict__ xT, u16* __restrict__ Wall) {
    __shared__ u16 t[128 * 136];
    const int tid = threadIdx.x;
    if (blockIdx.z == 8) {
        int gid = (blockIdx.y * 16 + blockIdx.x) * 256 + tid;
#pragma unroll
        for (int p = 0; p < 12; ++p) {
            int i = p * 16384 + gid;
            int which = i >> 16, j = i & 65535;
            const float* src = (which == 0) ? Wq : (which == 1 ? Wk : Wv);
            float4 v = ((const float4*)src)[j];
            ushort4 o;
            o.x = f2bf(v.x); o.y = f2bf(v.y); o.z = f2bf(v.z); o.w = f2bf(v.w);
            ((ushort4*)Wall)[i] = o;
        }
        return;
    }
    const int z = blockIdx.z, b = z & 3, c0 = blockIdx.y * 128, l0 = blockIdx.x * 128;
    const float* src = (z < 4) ? x1 : x2;
    u16* dbase = xT + (size_t)(z >> 2) * 4194304;
    const float* sp = src + ((size_t)b * DM + c0) * L_SEQ + l0;
#pragma unroll
    for (int p = 0; p < 16; ++p) {
        int id = p * 256 + tid;
        int ci = id >> 5, f4 = id & 31;
        float4 v = *(const float4*)(sp + (size_t)ci * L_SEQ + f4 * 4);
        u16x4 o;
        o[0] = f2bf(v.x); o[1] = f2bf(v.y); o[2] = f2bf(v.z); o[3] = f2bf(v.w);
        int pu = f4 ^ ((ci >> 3) & 7);           // swizzled 4-elem unit
        *(u16x4*)(t + ci * 136 + pu * 4) = o;
    }
    __syncthreads();
    u16* dp = dbase + ((size_t)b * L_SEQ + l0) * DM + c0;
#pragma unroll
    for (int p = 0; p < 8; ++p) {
        int id = p * 256 + tid;
        int lj = id >> 4, c8 = id & 15;
        int uj = lj >> 2, wj = lj & 3;
        u16x8 o;
#pragma unroll
        for (int i = 0; i < 8; ++i) {
            int row = c8 * 8 + i;                // row>>3 == c8
            o[i] = t[row * 136 + ((uj ^ (c8 & 7)) * 4 + wj)];
        }
        *(u16x8*)(dp + (size_t)lj * DM + c8 * 8) = o;
    }
}

// ---------------- fused QKV projection GEMM: ping-pong, unroll-2, const LDS bases ----------------
#define PROJ_BODY(AB, BB, NAB, NBB, DO_STAGE)                                   \
    {                                                                           \
        __syncthreads();                                                        \
        if (DO_STAGE) {                                                         \
            lds_load16(pA0, smem + (NAB) + sd0);                                \
            lds_load16(pA1, smem + (NAB) + sd1);                                \
            lds_load16(pB0, smem + (NBB) + sd0);                                \
            lds_load16(pB1, smem + (NBB) + sd1);                                \
            pA0 += 32; pA1 += 32; pB0 += 32; pB1 += 32;                         \
        }                                                                       \
        bf16x8 af[4], bfr[4];                                                   \
        _Pragma("unroll")                                                       \
        for (int mt = 0; mt < 4; ++mt)                                          \
            af[mt] = *(const bf16x8*)(smem + (AB) + aoffb[mt]);                 \
        _Pragma("unroll")                                                       \
        for (int nt = 0; nt < 4; ++nt)                                          \
            bfr[nt] = *(const bf16x8*)(smem + (BB) + boffb[nt]);                \
        _Pragma("unroll")                                                       \
        for (int mt = 0; mt < 4; ++mt)                                          \
            _Pragma("unroll")                                                   \
            for (int nt = 0; nt < 4; ++nt)                                      \
                acc[mt][nt] = __builtin_amdgcn_mfma_f32_16x16x32_bf16(          \
                    af[mt], bfr[nt], acc[mt][nt], 0, 0, 0);                     \
    }

__launch_bounds__(256, 3)
__global__ void proj_gemm(const u16* __restrict__ x1T, const u16* __restrict__ x2T,
                          const u16* __restrict__ Wall,
                          const float* __restrict__ bq, const float* __restrict__ bk,
                          const float* __restrict__ bv,
                          u16* __restrict__ Qo, u16* __restrict__ Ko, u16* __restrict__ Vto) {
    __shared__ __align__(16) char smem[34816];
    // A0 @0, B0 @8192, A1 @16384, B1 @24576
    const int by = blockIdx.y;
    const int b = by / 3, pj = by % 3;
    const int m0 = (blockIdx.x >> 2) * 128, n0 = (blockIdx.x & 3) * 128;
    const u16* xT = (pj == 0) ? x1T : x2T;
    const u16* W = Wall + (size_t)pj * 262144;
    const float* bias = (pj == 0) ? bq : (pj == 1 ? bk : bv);
    const float scale = (pj == 0) ? 0.18033688011112042f : 1.0f; // (1/8)*log2(e)

    const int tid = threadIdx.x;
    const int w = tid >> 6, lane = tid & 63;
    const int lm = lane & 15, lq = lane >> 4;
    const int wrow = (w & 1) * 64, wcol = (w >> 1) * 64;

    // staging sources (advanced incrementally); LDS dests as byte offsets
    const u16 *pA0, *pA1, *pB0, *pB1;
    {
        int s0 = tid, r0 = s0 >> 2, c0 = (s0 & 3) ^ (r0 & 3);
        int s1 = 256 + tid, r1 = s1 >> 2, c1 = (s1 & 3) ^ (r1 & 3);
        pA0 = xT + ((size_t)b * L_SEQ + m0 + r0) * DM + c0 * 8;
        pA1 = xT + ((size_t)b * L_SEQ + m0 + r1) * DM + c1 * 8;
        pB0 = W + (size_t)(n0 + r0) * DM + c0 * 8;
        pB1 = W + (size_t)(n0 + r1) * DM + c1 * 8;
    }
    const int sd0 = w * 1024;            // (w*64)*16 bytes
    const int sd1 = 4096 + w * 1024;

    // per-lane fragment byte offsets (loop-invariant)
    int aoffb[4], boffb[4];
#pragma unroll
    for (int mt = 0; mt < 4; ++mt) {
        int r = wrow + mt * 16 + lm;
        aoffb[mt] = r * 64 + (lq ^ (r & 3)) * 16;
    }
#pragma unroll
    for (int nt = 0; nt < 4; ++nt) {
        int r = wcol + nt * 16 + lm;
        boffb[nt] = r * 64 + (lq ^ (r & 3)) * 16;
    }

    f32x4 acc[4][4];
#pragma unroll
    for (int mt = 0; mt < 4; ++mt)
#pragma unroll
        for (int nt = 0; nt < 4; ++nt) acc[mt][nt] = (f32x4){0.f, 0.f, 0.f, 0.f};

    // prologue: tile 0 into A0/B0
    lds_load16(pA0, smem + 0 + sd0);
    lds_load16(pA1, smem + 0 + sd1);
    lds_load16(pB0, smem + 8192 + sd0);
    lds_load16(pB1, smem + 8192 + sd1);
    pA0 += 32; pA1 += 32; pB0 += 32; pB1 += 32;

    for (int kt2 = 0; kt2 < 8; ++kt2) {
        PROJ_BODY(0, 8192, 16384, 24576, true)          // compute tile 2kt2 (buf0), stage 2kt2+1
        PROJ_BODY(16384, 24576, 0, 8192, (kt2 < 7))     // compute tile 2kt2+1 (buf1), stage 2kt2+2
    }

    float bvv[4];
#pragma unroll
    for (int nt = 0; nt < 4; ++nt) bvv[nt] = bias[n0 + wcol + nt * 16 + lm];

    // LDS epilogue with coalesced 16B stores for ALL outputs.
    __syncthreads();
    u16* epi = (u16*)smem;
    if (pj < 2) {
        u16* dst = (pj == 0) ? Qo : Ko;
#pragma unroll
        for (int mt = 0; mt < 4; ++mt)
#pragma unroll
            for (int nt = 0; nt < 4; ++nt) {
                int colL = wcol + nt * 16 + lm;
                int row0 = wrow + mt * 16 + lq * 4;
                u16x4 tv;
#pragma unroll
                for (int r = 0; r < 4; ++r) tv[r] = f2bf((acc[mt][nt][r] + bvv[nt]) * scale);
                int pu = (row0 >> 2) ^ ((colL >> 3) & 7);
                *(u16x4*)(epi + colL * 136 + pu * 4) = tv;
            }
        __syncthreads();
#pragma unroll
        for (int p = 0; p < 8; ++p) {
            int id = p * 256 + tid;
            int rr = id >> 4, ch = id & 15;
            int ur = rr >> 2, wr = rr & 3;
            u16x8 vv;
#pragma unroll
            for (int j = 0; j < 8; ++j) {
                int col = ch * 8 + j;            // col>>3 == ch
                vv[j] = epi[col * 136 + ((ur ^ (ch & 7)) * 4 + wr)];
            }
            *(u16x8*)(dst + ((size_t)b * L_SEQ + m0 + rr) * DM + n0 + ch * 8) = vv;
        }
    } else {
#pragma unroll
        for (int mt = 0; mt < 4; ++mt)
#pragma unroll
            for (int nt = 0; nt < 4; ++nt) {
                int colL = wcol + nt * 16 + lm;
                int row0 = wrow + mt * 16 + lq * 4;
                u16x4 tv;
#pragma unroll
                for (int r = 0; r < 4; ++r) tv[r] = f2bf(acc[mt][nt][r] + bvv[nt]);
                *(u16x4*)(epi + colL * 136 + row0) = tv;
            }
        __syncthreads();
#pragma unroll
        for (int p = 0; p < 8; ++p) {
            int id = p * 256 + tid;
            int rr = id >> 4, ch = id & 15;
            u16x8 vv = *(const u16x8*)(epi + rr * 136 + ch * 8);
            *(u16x8*)(Vto + ((size_t)b * DM + n0 + rr) * L_SEQ + m0 + ch * 8) = vv;
        }
    }
}

// ---------------- flash attention: pair body + odd/even wave stagger (anti-lockstep) ----------------
// Round-11: MfmaUtil+VALUBusy SUM to 77% instead of overlapping (m114: separate pipes
// co-schedule when fed by DIFFERENT waves) -> the 8 waves march in lockstep through
// QK(MFMA)/softmax(VALU)/PV(MFMA). Sub-a and sub-b of a pair are independent and
// commutative (both staged before the barrier; accumulators are pure sums), so odd
// waves process (b,a) while even waves process (a,b): at any instant half the waves
// feed the matrix pipe while half feed the VALU pipe. Wave-uniform branch, no extra
// registers/barriers. T5 setprio(1) around MFMA clusters now that role-split exists.
#define ATTN_SUB(KB, VB)                                                        \
    {                                                                           \
        bf16x8 af0 = *(const bf16x8*)(smem + (KB) + koffb[0]);                  \
        bf16x8 af1 = *(const bf16x8*)(smem + (KB) + koffb[1]);                  \
        bf16x8 af2 = *(const bf16x8*)(smem + (KB) + koffb[2]);                  \
        bf16x8 af3 = *(const bf16x8*)(smem + (KB) + koffb[3]);                  \
        __builtin_amdgcn_s_setprio(1);                                          \
        f32x16 s = __builtin_amdgcn_mfma_f32_32x32x16_bf16(af0, qf[0], z16,     \
                                                           0, 0, 0);            \
        s = __builtin_amdgcn_mfma_f32_32x32x16_bf16(af1, qf[1], s, 0, 0, 0);    \
        s = __builtin_amdgcn_mfma_f32_32x32x16_bf16(af2, qf[2], s, 0, 0, 0);    \
        s = __builtin_amdgcn_mfma_f32_32x32x16_bf16(af3, qf[3], s, 0, 0, 0);    \
        __builtin_amdgcn_s_setprio(0);                                          \
        uint2 pw[4];                                                            \
        _Pragma("unroll")                                                       \
        for (int g2 = 0; g2 < 4; ++g2) {                                        \
            float p0 = __builtin_amdgcn_exp2f(s[4 * g2 + 0]);                   \
            float p1 = __builtin_amdgcn_exp2f(s[4 * g2 + 1]);                   \
            float p2 = __builtin_amdgcn_exp2f(s[4 * g2 + 2]);                   \
            float p3 = __builtin_amdgcn_exp2f(s[4 * g2 + 3]);                   \
            pw[g2].x = pk_bf16(p0, p1);                                         \
            pw[g2].y = pk_bf16(p2, p3);                                         \
        }                                                                       \
        __builtin_amdgcn_s_setprio(1);                                          \
        _Pragma("unroll")                                                       \
        for (int c2 = 0; c2 < 2; ++c2) {                                        \
            uint2 pa = pw[2 * c2], pb = pw[2 * c2 + 1];                         \
            u32x2 rx = __builtin_amdgcn_permlane32_swap(pa.x, pb.x, false, false); \
            u32x2 ry = __builtin_amdgcn_permlane32_swap(pa.y, pb.y, false, false); \
            uint4 pu;                                                           \
            pu.x = rx[0]; pu.y = ry[0]; pu.z = rx[1]; pu.w = ry[1];             \
            bf16x8 pf;                                                          \
            __builtin_memcpy(&pf, &pu, 16);                                     \
            l_acc = __builtin_amdgcn_mfma_f32_32x32x16_bf16(pf, ones8, l_acc,   \
                                                            0, 0, 0);           \
            _Pragma("unroll")                                                   \
            for (int dt = 0; dt < 2; ++dt) {                                    \
                bf16x8 vf = *(const bf16x8*)(smem + (VB) + voffb[c2 * 2 + dt]); \
                o_acc[dt] = __builtin_amdgcn_mfma_f32_32x32x16_bf16(            \
                    pf, vf, o_acc[dt], 0, 0, 0);                                \
            }                                                                   \
        }                                                                       \
        __builtin_amdgcn_s_setprio(0);                                          \
    }

#define ATTN_PAIR(KB, VB, NKB, NVB, DO_STAGE)                                   \
    {                                                                           \
        __syncthreads();                                                        \
        if (DO_STAGE) {                                                         \
            lds_load16(pKa, smem + (NKB) + sdb);                                \
            lds_load16(pKb, smem + (NKB) + 8192 + sdb);                         \
            lds_load16(pVa, smem + (NVB) + sdb);                                \
            lds_load16(pVb, smem + (NVB) + 8192 + sdb);                         \
            pKa += 128 * DM; pKb += 128 * DM; pVa += 128; pVb += 128;           \
        }                                                                       \
        if (wodd) {                                                             \
            ATTN_SUB((KB) + 8192, (VB) + 8192)                                  \
            ATTN_SUB(KB, VB)                                                    \
        } else {                                                                \
            ATTN_SUB(KB, VB)                                                    \
            ATTN_SUB((KB) + 8192, (VB) + 8192)                                  \
        }                                                                       \
    }

__launch_bounds__(512, 4)
__global__ void attn(const u16* __restrict__ Q, const u16* __restrict__ K,
                     const u16* __restrict__ Vt, float* __restrict__ out) {
    __shared__ __align__(16) char smem[65536];
    // pair0: K @0 (a@0,b@8192), V @32768 (a,b@+8192); pair1: K @16384, V @49152
    // Q staged through K-pair0 (16KB); epilogue overlay: o_lds @0 (33.8KB), l @33792
    float* l_lds = (float*)(smem + 33792);
    float* o_lds = (float*)smem;

    const int i = blockIdx.x;
    const int g = i & 7, r_ = i >> 3;
    const int qb = r_ & 15, bh = ((r_ >> 4) << 3) + g;
    const int h_ = bh >> 2, b = bh & 3;

    const int tid = threadIdx.x, w = tid >> 6, lane = tid & 63;
    const int q0 = qb * 128;
    const int lm32 = lane & 31, hi = lane >> 5;
    const int qg = w & 3, hk = w >> 2;
    const int qrow = qg * 32 + lm32;
    const int wodd = w & 1;   // wave-uniform sub-order stagger

    const u16* Qb = Q + ((size_t)b * L_SEQ + q0) * DM + h_ * 64;
    const u16* Kb = K + (size_t)b * L_SEQ * DM + h_ * 64;
    const u16* Vb = Vt + ((size_t)b * DM + h_ * 64) * L_SEQ;

    // staging sources (1 slot of 16B per thread per buffer) + LDS dest byte offset
    const u16 *pKa, *pKb, *pVa, *pVb;
    const int sdb = w * 1024;   // (w*64)*16 bytes, wave-uniform
    {
        int r = tid >> 3, cc = (tid & 7) ^ swz(r);
        pKa = Kb + (size_t)r * DM + cc * 8;
        pKb = pKa + (size_t)64 * DM;          // rows 64-127 of the pair
        pVa = Vb + (size_t)r * L_SEQ + cc * 8;
        pVb = pVa + 64;                       // k-cols 64-127 of the pair
    }

    // loop-invariant fragment byte offsets (sub-b adds +8192 at use site)
    const int rk = hk * 32 + lm32;
    int koffb[4], voffb[4];
#pragma unroll
    for (int c = 0; c < 4; ++c)
        koffb[c] = rk * 128 + ((2 * c + hi) ^ swz(rk)) * 16;
#pragma unroll
    for (int c2 = 0; c2 < 2; ++c2)
#pragma unroll
        for (int dt = 0; dt < 2; ++dt) {
            int d = dt * 32 + lm32;
            int kc = hk * 4 + c2 * 2 + hi;
            voffb[c2 * 2 + dt] = d * 128 + (kc ^ swz(d)) * 16;
        }

    // stage Q (128x64 = 16KB) through K-pair0 buffers
#pragma unroll
    for (int j = 0; j < 2; ++j) {
        int s = j * 512 + tid;
        int r = s >> 3, cc = (s & 7) ^ swz(r);
        lds_load16(Qb + (size_t)r * DM + cc * 8, smem + j * 8192 + sdb);
    }
    __syncthreads();
    bf16x8 qf[4];
#pragma unroll
    for (int c = 0; c < 4; ++c) {
        int slot = (2 * c + hi) ^ swz(qrow);
        qf[c] = *(const bf16x8*)(smem + qrow * 128 + slot * 16);
    }
    __syncthreads();   // Q reads done; K bufs reusable

    const f32x16 z16 = zero16();   // persistent zero C-operand for QK^T
    f32x16 o_acc[2];
    o_acc[0] = zero16(); o_acc[1] = zero16();
    f32x16 l_acc = zero16();       // row-sum accumulator (l via MFMA)
    bf16x8 ones8;
    {
        u16 one = 0x3F80;          // bf16 1.0
#pragma unroll
        for (int j = 0; j < 8; ++j) ((u16*)&ones8)[j] = one;
    }

    // prologue: stage pair 0 into K@0 / V@32768
    lds_load16(pKa, smem + 0 + sdb);
    lds_load16(pKb, smem + 8192 + sdb);
    lds_load16(pVa, smem + 32768 + sdb);
    lds_load16(pVb, smem + 40960 + sdb);
    pKa += 128 * DM; pKb += 128 * DM; pVa += 128; pVb += 128;

    for (int kt2 = 0; kt2 < 8; ++kt2) {
        ATTN_PAIR(0,     32768, 16384, 49152, true)        // pair 2k, stage pair 2k+1
        ATTN_PAIR(16384, 49152, 0,     32768, (kt2 < 7))   // pair 2k+1, stage pair 2k+2
    }

    __syncthreads();   // kv bufs dead; overlay o_lds
    // l: per lane l_acc[4*g2+r] = l[q = r + 8*g2 + 4*hi] (col-independent).
    if (lm32 == 0) {
#pragma unroll
        for (int g2 = 0; g2 < 4; ++g2)
#pragma unroll
            for (int r = 0; r < 4; ++r)
                l_lds[hk * 128 + qg * 32 + r + 8 * g2 + 4 * hi] = l_acc[4 * g2 + r];
    }
    if (hk == 0) {
#pragma unroll
        for (int dt = 0; dt < 2; ++dt) {
            int d = dt * 32 + lm32;
#pragma unroll
            for (int g2 = 0; g2 < 4; ++g2) {
                f32x4 vq;
#pragma unroll
                for (int r = 0; r < 4; ++r) vq[r] = o_acc[dt][4 * g2 + r];
                *(f32x4*)(o_lds + d * 132 + qg * 32 + 8 * g2 + 4 * hi) = vq;
            }
        }
    }
    __syncthreads();
    if (hk == 1) {
#pragma unroll
        for (int dt = 0; dt < 2; ++dt) {
            int d = dt * 32 + lm32;
#pragma unroll
            for (int g2 = 0; g2 < 4; ++g2) {
                float* ad = o_lds + d * 132 + qg * 32 + 8 * g2 + 4 * hi;
                f32x4 cur = *(f32x4*)ad;
#pragma unroll
                for (int r = 0; r < 4; ++r) cur[r] += o_acc[dt][4 * g2 + r];
                *(f32x4*)ad = cur;
            }
        }
    }
    __syncthreads();
    float* ob = out + ((size_t)b * DM + h_ * 64) * L_SEQ + q0;
#pragma unroll
    for (int p = 0; p < 4; ++p) {
        int id = p * 512 + tid;
        int d = id >> 5, rc = id & 31;
        f32x4 vv = *(const f32x4*)(o_lds + d * 132 + rc * 4);
        f32x4 la = *(const f32x4*)(l_lds + rc * 4);
        f32x4 lb = *(const f32x4*)(l_lds + 128 + rc * 4);
#pragma unroll
        for (int j = 0; j < 4; ++j) vv[j] *= 1.0f / (la[j] + lb[j]);
        *(f32x4*)(ob + (size_t)d * L_SEQ + rc * 4) = vv;
    }
}

extern "C" void kernel_launch(void* const* d_in, const int* in_sizes, int n_in,
                              void* d_out, int out_size, void* d_ws, size_t ws_size,
                              hipStream_t stream) {
    const float* x1 = (const float*)d_in[0];
    const float* x2 = (const float*)d_in[1];
    const float* Wq = (const float*)d_in[2];
    const float* bq = (const float*)d_in[3];
    const float* Wk = (const float*)d_in[4];
    const float* bk = (const float*)d_in[5];
    const float* Wv = (const float*)d_in[6];
    const float* bv = (const float*)d_in[7];
    float* out = (float*)d_out;

    char* ws = (char*)d_ws;
    u16* x1T = (u16*)(ws);
    u16* x2T = (u16*)(ws + 8388608);
    u16* Wall = (u16*)(ws + 16777216);
    u16* Qb  = (u16*)(ws + 18350080);
    u16* Kb  = (u16*)(ws + 26738688);
    u16* Vtb = (u16*)(ws + 35127296);

    prep<<<dim3(16, 4, 9), 256, 0, stream>>>(x1, x2, Wq, Wk, Wv, x1T, Wall);
    proj_gemm<<<dim3(64, 12), 256, 0, stream>>>(x1T, x2T, Wall, bq, bk, bv, Qb, Kb, Vtb);
    attn<<<512, 512, 0, stream>>>(Qb, Kb, Vtb, out);
}

// Round 12
// 158.016 us; speedup vs baseline: 1.1796x; 1.1796x over previous
//
#include <hip/hip_runtime.h>
#include <hip/hip_bf16.h>

#define L_SEQ 2048
#define DM 512

typedef short bf16x8 __attribute__((ext_vector_type(8)));
typedef float f32x4 __attribute__((ext_vector_type(4)));
typedef float f32x16 __attribute__((ext_vector_type(16)));
typedef unsigned short u16;
typedef u16 u16x8 __attribute__((ext_vector_type(8)));
typedef u16 u16x4 __attribute__((ext_vector_type(4)));
typedef unsigned int u32x2 __attribute__((ext_vector_type(2)));

__device__ __forceinline__ u16 f2bf(float f) {
    unsigned int u = __float_as_uint(f);
    u += 0x7fffu + ((u >> 16) & 1u);
    return (u16)(u >> 16);
}

__device__ __forceinline__ unsigned int pk_bf16(float a, float b) {
    __hip_bfloat162 h = __float22bfloat162_rn(float2{a, b});
    unsigned int u;
    __builtin_memcpy(&u, &h, 4);
    return u;
}

__device__ __forceinline__ void lds_load16(const void* g, void* l) {
    __builtin_amdgcn_global_load_lds(
        (const __attribute__((address_space(1))) unsigned int*)g,
        (__attribute__((address_space(3))) unsigned int*)l,
        16, 0, 0);
}

__device__ __forceinline__ f32x16 zero16() {
    f32x16 z;
#pragma unroll
    for (int i = 0; i < 16; ++i) z[i] = 0.f;
    return z;
}

// wide-period row swizzle: mixes ALL row bits into the 8-slot index (rows up to 128)
__device__ __forceinline__ int swz(int r) { return (r & 7) ^ ((r >> 3) & 7); }

// ---------------- prep: x transpose+cast (z<8) and weight casts (z==8) ----------------
__global__ void prep(const float* __restrict__ x1, const float* __restrict__ x2,
                     const float* __restrict__ Wq, const float* __restrict__ Wk,
                     const float* __restrict__ Wv,
                     u16* __restrict__ xT, u16* __restrict__ Wall) {
    __shared__ u16 t[128 * 136];
    const int tid = threadIdx.x;
    if (blockIdx.z == 8) {
        int gid = (blockIdx.y * 16 + blockIdx.x) * 256 + tid;
#pragma unroll
        for (int p = 0; p < 12; ++p) {
            int i = p * 16384 + gid;
            int which = i >> 16, j = i & 65535;
            const float* src = (which == 0) ? Wq : (which == 1 ? Wk : Wv);
            float4 v = ((const float4*)src)[j];
            ushort4 o;
            o.x = f2bf(v.x); o.y = f2bf(v.y); o.z = f2bf(v.z); o.w = f2bf(v.w);
            ((ushort4*)Wall)[i] = o;
        }
        return;
    }
    const int z = blockIdx.z, b = z & 3, c0 = blockIdx.y * 128, l0 = blockIdx.x * 128;
    const float* src = (z < 4) ? x1 : x2;
    u16* dbase = xT + (size_t)(z >> 2) * 4194304;
    const float* sp = src + ((size_t)b * DM + c0) * L_SEQ + l0;
#pragma unroll
    for (int p = 0; p < 16; ++p) {
        int id = p * 256 + tid;
        int ci = id >> 5, f4 = id & 31;
        float4 v = *(const float4*)(sp + (size_t)ci * L_SEQ + f4 * 4);
        u16x4 o;
        o[0] = f2bf(v.x); o[1] = f2bf(v.y); o[2] = f2bf(v.z); o[3] = f2bf(v.w);
        int pu = f4 ^ ((ci >> 3) & 7);           // swizzled 4-elem unit
        *(u16x4*)(t + ci * 136 + pu * 4) = o;
    }
    __syncthreads();
    u16* dp = dbase + ((size_t)b * L_SEQ + l0) * DM + c0;
#pragma unroll
    for (int p = 0; p < 8; ++p) {
        int id = p * 256 + tid;
        int lj = id >> 4, c8 = id & 15;
        int uj = lj >> 2, wj = lj & 3;
        u16x8 o;
#pragma unroll
        for (int i = 0; i < 8; ++i) {
            int row = c8 * 8 + i;                // row>>3 == c8
            o[i] = t[row * 136 + ((uj ^ (c8 & 7)) * 4 + wj)];
        }
        *(u16x8*)(dp + (size_t)lj * DM + c8 * 8) = o;
    }
}

// ---------------- fused QKV projection GEMM: ping-pong, unroll-2, const LDS bases ----------------
#define PROJ_BODY(AB, BB, NAB, NBB, DO_STAGE)                                   \
    {                                                                           \
        __syncthreads();                                                        \
        if (DO_STAGE) {                                                         \
            lds_load16(pA0, smem + (NAB) + sd0);                                \
            lds_load16(pA1, smem + (NAB) + sd1);                                \
            lds_load16(pB0, smem + (NBB) + sd0);                                \
            lds_load16(pB1, smem + (NBB) + sd1);                                \
            pA0 += 32; pA1 += 32; pB0 += 32; pB1 += 32;                         \
        }                                                                       \
        bf16x8 af[4], bfr[4];                                                   \
        _Pragma("unroll")                                                       \
        for (int mt = 0; mt < 4; ++mt)                                          \
            af[mt] = *(const bf16x8*)(smem + (AB) + aoffb[mt]);                 \
        _Pragma("unroll")                                                       \
        for (int nt = 0; nt < 4; ++nt)                                          \
            bfr[nt] = *(const bf16x8*)(smem + (BB) + boffb[nt]);                \
        _Pragma("unroll")                                                       \
        for (int mt = 0; mt < 4; ++mt)                                          \
            _Pragma("unroll")                                                   \
            for (int nt = 0; nt < 4; ++nt)                                      \
                acc[mt][nt] = __builtin_amdgcn_mfma_f32_16x16x32_bf16(          \
                    af[mt], bfr[nt], acc[mt][nt], 0, 0, 0);                     \
    }

__launch_bounds__(256, 3)
__global__ void proj_gemm(const u16* __restrict__ x1T, const u16* __restrict__ x2T,
                          const u16* __restrict__ Wall,
                          const float* __restrict__ bq, const float* __restrict__ bk,
                          const float* __restrict__ bv,
                          u16* __restrict__ Qo, u16* __restrict__ Ko, u16* __restrict__ Vto) {
    __shared__ __align__(16) char smem[34816];
    // A0 @0, B0 @8192, A1 @16384, B1 @24576
    const int by = blockIdx.y;
    const int b = by / 3, pj = by % 3;
    const int m0 = (blockIdx.x >> 2) * 128, n0 = (blockIdx.x & 3) * 128;
    const u16* xT = (pj == 0) ? x1T : x2T;
    const u16* W = Wall + (size_t)pj * 262144;
    const float* bias = (pj == 0) ? bq : (pj == 1 ? bk : bv);
    const float scale = (pj == 0) ? 0.18033688011112042f : 1.0f; // (1/8)*log2(e)

    const int tid = threadIdx.x;
    const int w = tid >> 6, lane = tid & 63;
    const int lm = lane & 15, lq = lane >> 4;
    const int wrow = (w & 1) * 64, wcol = (w >> 1) * 64;

    // staging sources (advanced incrementally); LDS dests as byte offsets
    const u16 *pA0, *pA1, *pB0, *pB1;
    {
        int s0 = tid, r0 = s0 >> 2, c0 = (s0 & 3) ^ (r0 & 3);
        int s1 = 256 + tid, r1 = s1 >> 2, c1 = (s1 & 3) ^ (r1 & 3);
        pA0 = xT + ((size_t)b * L_SEQ + m0 + r0) * DM + c0 * 8;
        pA1 = xT + ((size_t)b * L_SEQ + m0 + r1) * DM + c1 * 8;
        pB0 = W + (size_t)(n0 + r0) * DM + c0 * 8;
        pB1 = W + (size_t)(n0 + r1) * DM + c1 * 8;
    }
    const int sd0 = w * 1024;            // (w*64)*16 bytes
    const int sd1 = 4096 + w * 1024;

    // per-lane fragment byte offsets (loop-invariant)
    int aoffb[4], boffb[4];
#pragma unroll
    for (int mt = 0; mt < 4; ++mt) {
        int r = wrow + mt * 16 + lm;
        aoffb[mt] = r * 64 + (lq ^ (r & 3)) * 16;
    }
#pragma unroll
    for (int nt = 0; nt < 4; ++nt) {
        int r = wcol + nt * 16 + lm;
        boffb[nt] = r * 64 + (lq ^ (r & 3)) * 16;
    }

    f32x4 acc[4][4];
#pragma unroll
    for (int mt = 0; mt < 4; ++mt)
#pragma unroll
        for (int nt = 0; nt < 4; ++nt) acc[mt][nt] = (f32x4){0.f, 0.f, 0.f, 0.f};

    // prologue: tile 0 into A0/B0
    lds_load16(pA0, smem + 0 + sd0);
    lds_load16(pA1, smem + 0 + sd1);
    lds_load16(pB0, smem + 8192 + sd0);
    lds_load16(pB1, smem + 8192 + sd1);
    pA0 += 32; pA1 += 32; pB0 += 32; pB1 += 32;

    for (int kt2 = 0; kt2 < 8; ++kt2) {
        PROJ_BODY(0, 8192, 16384, 24576, true)          // compute tile 2kt2 (buf0), stage 2kt2+1
        PROJ_BODY(16384, 24576, 0, 8192, (kt2 < 7))     // compute tile 2kt2+1 (buf1), stage 2kt2+2
    }

    float bvv[4];
#pragma unroll
    for (int nt = 0; nt < 4; ++nt) bvv[nt] = bias[n0 + wcol + nt * 16 + lm];

    // LDS epilogue with coalesced 16B stores for ALL outputs.
    __syncthreads();
    u16* epi = (u16*)smem;
    if (pj < 2) {
        u16* dst = (pj == 0) ? Qo : Ko;
#pragma unroll
        for (int mt = 0; mt < 4; ++mt)
#pragma unroll
            for (int nt = 0; nt < 4; ++nt) {
                int colL = wcol + nt * 16 + lm;
                int row0 = wrow + mt * 16 + lq * 4;
                u16x4 tv;
#pragma unroll
                for (int r = 0; r < 4; ++r) tv[r] = f2bf((acc[mt][nt][r] + bvv[nt]) * scale);
                int pu = (row0 >> 2) ^ ((colL >> 3) & 7);
                *(u16x4*)(epi + colL * 136 + pu * 4) = tv;
            }
        __syncthreads();
#pragma unroll
        for (int p = 0; p < 8; ++p) {
            int id = p * 256 + tid;
            int rr = id >> 4, ch = id & 15;
            int ur = rr >> 2, wr = rr & 3;
            u16x8 vv;
#pragma unroll
            for (int j = 0; j < 8; ++j) {
                int col = ch * 8 + j;            // col>>3 == ch
                vv[j] = epi[col * 136 + ((ur ^ (ch & 7)) * 4 + wr)];
            }
            *(u16x8*)(dst + ((size_t)b * L_SEQ + m0 + rr) * DM + n0 + ch * 8) = vv;
        }
    } else {
#pragma unroll
        for (int mt = 0; mt < 4; ++mt)
#pragma unroll
            for (int nt = 0; nt < 4; ++nt) {
                int colL = wcol + nt * 16 + lm;
                int row0 = wrow + mt * 16 + lq * 4;
                u16x4 tv;
#pragma unroll
                for (int r = 0; r < 4; ++r) tv[r] = f2bf(acc[mt][nt][r] + bvv[nt]);
                *(u16x4*)(epi + colL * 136 + row0) = tv;
            }
        __syncthreads();
#pragma unroll
        for (int p = 0; p < 8; ++p) {
            int id = p * 256 + tid;
            int rr = id >> 4, ch = id & 15;
            u16x8 vv = *(const u16x8*)(epi + rr * 136 + ch * 8);
            *(u16x8*)(Vto + ((size_t)b * DM + n0 + rr) * L_SEQ + m0 + ch * 8) = vv;
        }
    }
}

// ---------------- flash attention: pair body + branchless wave stagger ----------------
// Round-12: R11's if/else stagger duplicated the body -> scratch spill (WRITE 16->116MB).
// Same mechanism, spill-proof form: SINGLE code path, the sub-tile order is a runtime
// wave-uniform byte offset (soA = (w&1)<<13, soB = 8192-soA). Even waves compute
// (sub-a, sub-b), odd waves (sub-b, sub-a) -> at any instant ~half the waves feed the
// matrix pipe while half feed the VALU pipe (m114: pipes overlap when fed by different
// waves; R10 counters show sum-not-max = lockstep). Accumulators are pure sums, so
// per-wave tile order is semantics-preserving. Body is R10's verbatim otherwise.
#define ATTN_SUB(KB, VB)                                                        \
    {                                                                           \
        bf16x8 af0 = *(const bf16x8*)(smem + (KB) + koffb[0]);                  \
        f32x16 s = __builtin_amdgcn_mfma_f32_32x32x16_bf16(af0, qf[0], z16,     \
                                                           0, 0, 0);            \
        _Pragma("unroll")                                                       \
        for (int c = 1; c < 4; ++c) {                                           \
            bf16x8 af = *(const bf16x8*)(smem + (KB) + koffb[c]);               \
            s = __builtin_amdgcn_mfma_f32_32x32x16_bf16(af, qf[c], s, 0, 0, 0); \
        }                                                                       \
        uint2 pw[4];                                                            \
        _Pragma("unroll")                                                       \
        for (int g2 = 0; g2 < 4; ++g2) {                                        \
            float p0 = __builtin_amdgcn_exp2f(s[4 * g2 + 0]);                   \
            float p1 = __builtin_amdgcn_exp2f(s[4 * g2 + 1]);                   \
            float p2 = __builtin_amdgcn_exp2f(s[4 * g2 + 2]);                   \
            float p3 = __builtin_amdgcn_exp2f(s[4 * g2 + 3]);                   \
            pw[g2].x = pk_bf16(p0, p1);                                         \
            pw[g2].y = pk_bf16(p2, p3);                                         \
        }                                                                       \
        _Pragma("unroll")                                                       \
        for (int c2 = 0; c2 < 2; ++c2) {                                        \
            uint2 pa = pw[2 * c2], pb = pw[2 * c2 + 1];                         \
            u32x2 rx = __builtin_amdgcn_permlane32_swap(pa.x, pb.x, false, false); \
            u32x2 ry = __builtin_amdgcn_permlane32_swap(pa.y, pb.y, false, false); \
            uint4 pu;                                                           \
            pu.x = rx[0]; pu.y = ry[0]; pu.z = rx[1]; pu.w = ry[1];             \
            bf16x8 pf;                                                          \
            __builtin_memcpy(&pf, &pu, 16);                                     \
            l_acc = __builtin_amdgcn_mfma_f32_32x32x16_bf16(pf, ones8, l_acc,   \
                                                            0, 0, 0);           \
            _Pragma("unroll")                                                   \
            for (int dt = 0; dt < 2; ++dt) {                                    \
                bf16x8 vf = *(const bf16x8*)(smem + (VB) + voffb[c2 * 2 + dt]); \
                o_acc[dt] = __builtin_amdgcn_mfma_f32_32x32x16_bf16(            \
                    pf, vf, o_acc[dt], 0, 0, 0);                                \
            }                                                                   \
        }                                                                       \
    }

#define ATTN_PAIR(KB, VB, NKB, NVB, DO_STAGE)                                   \
    {                                                                           \
        __syncthreads();                                                        \
        if (DO_STAGE) {                                                         \
            lds_load16(pKa, smem + (NKB) + sdb);                                \
            lds_load16(pKb, smem + (NKB) + 8192 + sdb);                         \
            lds_load16(pVa, smem + (NVB) + sdb);                                \
            lds_load16(pVb, smem + (NVB) + 8192 + sdb);                         \
            pKa += 128 * DM; pKb += 128 * DM; pVa += 128; pVb += 128;           \
        }                                                                       \
        ATTN_SUB((KB) + soA, (VB) + soA)                                        \
        ATTN_SUB((KB) + soB, (VB) + soB)                                        \
    }

__launch_bounds__(512, 4)
__global__ void attn(const u16* __restrict__ Q, const u16* __restrict__ K,
                     const u16* __restrict__ Vt, float* __restrict__ out) {
    __shared__ __align__(16) char smem[65536];
    // pair0: K @0 (a@0,b@8192), V @32768 (a,b@+8192); pair1: K @16384, V @49152
    // Q staged through K-pair0 (16KB); epilogue overlay: o_lds @0 (33.8KB), l @33792
    float* l_lds = (float*)(smem + 33792);
    float* o_lds = (float*)smem;

    const int i = blockIdx.x;
    const int g = i & 7, r_ = i >> 3;
    const int qb = r_ & 15, bh = ((r_ >> 4) << 3) + g;
    const int h_ = bh >> 2, b = bh & 3;

    const int tid = threadIdx.x, w = tid >> 6, lane = tid & 63;
    const int q0 = qb * 128;
    const int lm32 = lane & 31, hi = lane >> 5;
    const int qg = w & 3, hk = w >> 2;
    const int qrow = qg * 32 + lm32;
    const int soA = (w & 1) << 13;   // wave-uniform sub order: even (a,b), odd (b,a)
    const int soB = 8192 - soA;

    const u16* Qb = Q + ((size_t)b * L_SEQ + q0) * DM + h_ * 64;
    const u16* Kb = K + (size_t)b * L_SEQ * DM + h_ * 64;
    const u16* Vb = Vt + ((size_t)b * DM + h_ * 64) * L_SEQ;

    // staging sources (1 slot of 16B per thread per buffer) + LDS dest byte offset
    const u16 *pKa, *pKb, *pVa, *pVb;
    const int sdb = w * 1024;   // (w*64)*16 bytes, wave-uniform
    {
        int r = tid >> 3, cc = (tid & 7) ^ swz(r);
        pKa = Kb + (size_t)r * DM + cc * 8;
        pKb = pKa + (size_t)64 * DM;          // rows 64-127 of the pair
        pVa = Vb + (size_t)r * L_SEQ + cc * 8;
        pVb = pVa + 64;                       // k-cols 64-127 of the pair
    }

    // loop-invariant fragment byte offsets (sub base added at use site)
    const int rk = hk * 32 + lm32;
    int koffb[4], voffb[4];
#pragma unroll
    for (int c = 0; c < 4; ++c)
        koffb[c] = rk * 128 + ((2 * c + hi) ^ swz(rk)) * 16;
#pragma unroll
    for (int c2 = 0; c2 < 2; ++c2)
#pragma unroll
        for (int dt = 0; dt < 2; ++dt) {
            int d = dt * 32 + lm32;
            int kc = hk * 4 + c2 * 2 + hi;
            voffb[c2 * 2 + dt] = d * 128 + (kc ^ swz(d)) * 16;
        }

    // stage Q (128x64 = 16KB) through K-pair0 buffers
#pragma unroll
    for (int j = 0; j < 2; ++j) {
        int s = j * 512 + tid;
        int r = s >> 3, cc = (s & 7) ^ swz(r);
        lds_load16(Qb + (size_t)r * DM + cc * 8, smem + j * 8192 + sdb);
    }
    __syncthreads();
    bf16x8 qf[4];
#pragma unroll
    for (int c = 0; c < 4; ++c) {
        int slot = (2 * c + hi) ^ swz(qrow);
        qf[c] = *(const bf16x8*)(smem + qrow * 128 + slot * 16);
    }
    __syncthreads();   // Q reads done; K bufs reusable

    const f32x16 z16 = zero16();   // persistent zero C-operand for QK^T
    f32x16 o_acc[2];
    o_acc[0] = zero16(); o_acc[1] = zero16();
    f32x16 l_acc = zero16();       // row-sum accumulator (l via MFMA)
    bf16x8 ones8;
    {
        u16 one = 0x3F80;          // bf16 1.0
#pragma unroll
        for (int j = 0; j < 8; ++j) ((u16*)&ones8)[j] = one;
    }

    // prologue: stage pair 0 into K@0 / V@32768
    lds_load16(pKa, smem + 0 + sdb);
    lds_load16(pKb, smem + 8192 + sdb);
    lds_load16(pVa, smem + 32768 + sdb);
    lds_load16(pVb, smem + 40960 + sdb);
    pKa += 128 * DM; pKb += 128 * DM; pVa += 128; pVb += 128;

    for (int kt2 = 0; kt2 < 8; ++kt2) {
        ATTN_PAIR(0,     32768, 16384, 49152, true)        // pair 2k, stage pair 2k+1
        ATTN_PAIR(16384, 49152, 0,     32768, (kt2 < 7))   // pair 2k+1, stage pair 2k+2
    }

    __syncthreads();   // kv bufs dead; overlay o_lds
    // l: per lane l_acc[4*g2+r] = l[q = r + 8*g2 + 4*hi] (col-independent).
    if (lm32 == 0) {
#pragma unroll
        for (int g2 = 0; g2 < 4; ++g2)
#pragma unroll
            for (int r = 0; r < 4; ++r)
                l_lds[hk * 128 + qg * 32 + r + 8 * g2 + 4 * hi] = l_acc[4 * g2 + r];
    }
    if (hk == 0) {
#pragma unroll
        for (int dt = 0; dt < 2; ++dt) {
            int d = dt * 32 + lm32;
#pragma unroll
            for (int g2 = 0; g2 < 4; ++g2) {
                f32x4 vq;
#pragma unroll
                for (int r = 0; r < 4; ++r) vq[r] = o_acc[dt][4 * g2 + r];
                *(f32x4*)(o_lds + d * 132 + qg * 32 + 8 * g2 + 4 * hi) = vq;
            }
        }
    }
    __syncthreads();
    if (hk == 1) {
#pragma unroll
        for (int dt = 0; dt < 2; ++dt) {
            int d = dt * 32 + lm32;
#pragma unroll
            for (int g2 = 0; g2 < 4; ++g2) {
                float* ad = o_lds + d * 132 + qg * 32 + 8 * g2 + 4 * hi;
                f32x4 cur = *(f32x4*)ad;
#pragma unroll
                for (int r = 0; r < 4; ++r) cur[r] += o_acc[dt][4 * g2 + r];
                *(f32x4*)ad = cur;
            }
        }
    }
    __syncthreads();
    float* ob = out + ((size_t)b * DM + h_ * 64) * L_SEQ + q0;
#pragma unroll
    for (int p = 0; p < 4; ++p) {
        int id = p * 512 + tid;
        int d = id >> 5, rc = id & 31;
        f32x4 vv = *(const f32x4*)(o_lds + d * 132 + rc * 4);
        f32x4 la = *(const f32x4*)(l_lds + rc * 4);
        f32x4 lb = *(const f32x4*)(l_lds + 128 + rc * 4);
#pragma unroll
        for (int j = 0; j < 4; ++j) vv[j] *= 1.0f / (la[j] + lb[j]);
        *(f32x4*)(ob + (size_t)d * L_SEQ + rc * 4) = vv;
    }
}

extern "C" void kernel_launch(void* const* d_in, const int* in_sizes, int n_in,
                              void* d_out, int out_size, void* d_ws, size_t ws_size,
                              hipStream_t stream) {
    const float* x1 = (const float*)d_in[0];
    const float* x2 = (const float*)d_in[1];
    const float* Wq = (const float*)d_in[2];
    const float* bq = (const float*)d_in[3];
    const float* Wk = (const float*)d_in[4];
    const float* bk = (const float*)d_in[5];
    const float* Wv = (const float*)d_in[6];
    const float* bv = (const float*)d_in[7];
    float* out = (float*)d_out;

    char* ws = (char*)d_ws;
    u16* x1T = (u16*)(ws);
    u16* x2T = (u16*)(ws + 8388608);
    u16* Wall = (u16*)(ws + 16777216);
    u16* Qb  = (u16*)(ws + 18350080);
    u16* Kb  = (u16*)(ws + 26738688);
    u16* Vtb = (u16*)(ws + 35127296);

    prep<<<dim3(16, 4, 9), 256, 0, stream>>>(x1, x2, Wq, Wk, Wv, x1T, Wall);
    proj_gemm<<<dim3(64, 12), 256, 0, stream>>>(x1T, x2T, Wall, bq, bk, bv, Qb, Kb, Vtb);
    attn<<<512, 512, 0, stream>>>(Qb, Kb, Vtb, out);
}

// Round 13
// 154.439 us; speedup vs baseline: 1.2070x; 1.0232x over previous
//
#include <hip/hip_runtime.h>
#include <hip/hip_bf16.h>

#define L_SEQ 2048
#define DM 512

typedef short bf16x8 __attribute__((ext_vector_type(8)));
typedef float f32x4 __attribute__((ext_vector_type(4)));
typedef float f32x16 __attribute__((ext_vector_type(16)));
typedef unsigned short u16;
typedef u16 u16x8 __attribute__((ext_vector_type(8)));
typedef u16 u16x4 __attribute__((ext_vector_type(4)));
typedef unsigned int u32x2 __attribute__((ext_vector_type(2)));

__device__ __forceinline__ u16 f2bf(float f) {
    unsigned int u = __float_as_uint(f);
    u += 0x7fffu + ((u >> 16) & 1u);
    return (u16)(u >> 16);
}

__device__ __forceinline__ unsigned int pk_bf16(float a, float b) {
    __hip_bfloat162 h = __float22bfloat162_rn(float2{a, b});
    unsigned int u;
    __builtin_memcpy(&u, &h, 4);
    return u;
}

__device__ __forceinline__ void lds_load16(const void* g, void* l) {
    __builtin_amdgcn_global_load_lds(
        (const __attribute__((address_space(1))) unsigned int*)g,
        (__attribute__((address_space(3))) unsigned int*)l,
        16, 0, 0);
}

__device__ __forceinline__ f32x16 zero16() {
    f32x16 z;
#pragma unroll
    for (int i = 0; i < 16; ++i) z[i] = 0.f;
    return z;
}

// wide-period row swizzle: mixes ALL row bits into the 8-slot index (rows up to 128)
__device__ __forceinline__ int swz(int r) { return (r & 7) ^ ((r >> 3) & 7); }

// ---------------- prep: x transpose+cast (z<8) and weight casts (z==8) ----------------
__global__ void prep(const float* __restrict__ x1, const float* __restrict__ x2,
                     const float* __restrict__ Wq, const float* __restrict__ Wk,
                     const float* __restrict__ Wv,
                     u16* __restrict__ xT, u16* __restrict__ Wall) {
    __shared__ u16 t[128 * 136];
    const int tid = threadIdx.x;
    if (blockIdx.z == 8) {
        int gid = (blockIdx.y * 16 + blockIdx.x) * 256 + tid;
#pragma unroll
        for (int p = 0; p < 12; ++p) {
            int i = p * 16384 + gid;
            int which = i >> 16, j = i & 65535;
            const float* src = (which == 0) ? Wq : (which == 1 ? Wk : Wv);
            float4 v = ((const float4*)src)[j];
            ushort4 o;
            o.x = f2bf(v.x); o.y = f2bf(v.y); o.z = f2bf(v.z); o.w = f2bf(v.w);
            ((ushort4*)Wall)[i] = o;
        }
        return;
    }
    const int z = blockIdx.z, b = z & 3, c0 = blockIdx.y * 128, l0 = blockIdx.x * 128;
    const float* src = (z < 4) ? x1 : x2;
    u16* dbase = xT + (size_t)(z >> 2) * 4194304;
    const float* sp = src + ((size_t)b * DM + c0) * L_SEQ + l0;
#pragma unroll
    for (int p = 0; p < 16; ++p) {
        int id = p * 256 + tid;
        int ci = id >> 5, f4 = id & 31;
        float4 v = *(const float4*)(sp + (size_t)ci * L_SEQ + f4 * 4);
        u16x4 o;
        o[0] = f2bf(v.x); o[1] = f2bf(v.y); o[2] = f2bf(v.z); o[3] = f2bf(v.w);
        int pu = f4 ^ ((ci >> 3) & 7);           // swizzled 4-elem unit
        *(u16x4*)(t + ci * 136 + pu * 4) = o;
    }
    __syncthreads();
    u16* dp = dbase + ((size_t)b * L_SEQ + l0) * DM + c0;
#pragma unroll
    for (int p = 0; p < 8; ++p) {
        int id = p * 256 + tid;
        int lj = id >> 4, c8 = id & 15;
        int uj = lj >> 2, wj = lj & 3;
        u16x8 o;
#pragma unroll
        for (int i = 0; i < 8; ++i) {
            int row = c8 * 8 + i;                // row>>3 == c8
            o[i] = t[row * 136 + ((uj ^ (c8 & 7)) * 4 + wj)];
        }
        *(u16x8*)(dp + (size_t)lj * DM + c8 * 8) = o;
    }
}

// ---------------- fused QKV projection GEMM: ping-pong, unroll-2, const LDS bases ----------------
#define PROJ_BODY(AB, BB, NAB, NBB, DO_STAGE)                                   \
    {                                                                           \
        __syncthreads();                                                        \
        if (DO_STAGE) {                                                         \
            lds_load16(pA0, smem + (NAB) + sd0);                                \
            lds_load16(pA1, smem + (NAB) + sd1);                                \
            lds_load16(pB0, smem + (NBB) + sd0);                                \
            lds_load16(pB1, smem + (NBB) + sd1);                                \
            pA0 += 32; pA1 += 32; pB0 += 32; pB1 += 32;                         \
        }                                                                       \
        bf16x8 af[4], bfr[4];                                                   \
        _Pragma("unroll")                                                       \
        for (int mt = 0; mt < 4; ++mt)                                          \
            af[mt] = *(const bf16x8*)(smem + (AB) + aoffb[mt]);                 \
        _Pragma("unroll")                                                       \
        for (int nt = 0; nt < 4; ++nt)                                          \
            bfr[nt] = *(const bf16x8*)(smem + (BB) + boffb[nt]);                \
        _Pragma("unroll")                                                       \
        for (int mt = 0; mt < 4; ++mt)                                          \
            _Pragma("unroll")                                                   \
            for (int nt = 0; nt < 4; ++nt)                                      \
                acc[mt][nt] = __builtin_amdgcn_mfma_f32_16x16x32_bf16(          \
                    af[mt], bfr[nt], acc[mt][nt], 0, 0, 0);                     \
    }

__launch_bounds__(256, 3)
__global__ void proj_gemm(const u16* __restrict__ x1T, const u16* __restrict__ x2T,
                          const u16* __restrict__ Wall,
                          const float* __restrict__ bq, const float* __restrict__ bk,
                          const float* __restrict__ bv,
                          u16* __restrict__ Qo, u16* __restrict__ Ko, u16* __restrict__ Vto) {
    __shared__ __align__(16) char smem[34816];
    // A0 @0, B0 @8192, A1 @16384, B1 @24576
    const int by = blockIdx.y;
    const int b = by / 3, pj = by % 3;
    const int m0 = (blockIdx.x >> 2) * 128, n0 = (blockIdx.x & 3) * 128;
    const u16* xT = (pj == 0) ? x1T : x2T;
    const u16* W = Wall + (size_t)pj * 262144;
    const float* bias = (pj == 0) ? bq : (pj == 1 ? bk : bv);
    const float scale = (pj == 0) ? 0.18033688011112042f : 1.0f; // (1/8)*log2(e)

    const int tid = threadIdx.x;
    const int w = tid >> 6, lane = tid & 63;
    const int lm = lane & 15, lq = lane >> 4;
    const int wrow = (w & 1) * 64, wcol = (w >> 1) * 64;

    // staging sources (advanced incrementally); LDS dests as byte offsets
    const u16 *pA0, *pA1, *pB0, *pB1;
    {
        int s0 = tid, r0 = s0 >> 2, c0 = (s0 & 3) ^ (r0 & 3);
        int s1 = 256 + tid, r1 = s1 >> 2, c1 = (s1 & 3) ^ (r1 & 3);
        pA0 = xT + ((size_t)b * L_SEQ + m0 + r0) * DM + c0 * 8;
        pA1 = xT + ((size_t)b * L_SEQ + m0 + r1) * DM + c1 * 8;
        pB0 = W + (size_t)(n0 + r0) * DM + c0 * 8;
        pB1 = W + (size_t)(n0 + r1) * DM + c1 * 8;
    }
    const int sd0 = w * 1024;            // (w*64)*16 bytes
    const int sd1 = 4096 + w * 1024;

    // per-lane fragment byte offsets (loop-invariant)
    int aoffb[4], boffb[4];
#pragma unroll
    for (int mt = 0; mt < 4; ++mt) {
        int r = wrow + mt * 16 + lm;
        aoffb[mt] = r * 64 + (lq ^ (r & 3)) * 16;
    }
#pragma unroll
    for (int nt = 0; nt < 4; ++nt) {
        int r = wcol + nt * 16 + lm;
        boffb[nt] = r * 64 + (lq ^ (r & 3)) * 16;
    }

    f32x4 acc[4][4];
#pragma unroll
    for (int mt = 0; mt < 4; ++mt)
#pragma unroll
        for (int nt = 0; nt < 4; ++nt) acc[mt][nt] = (f32x4){0.f, 0.f, 0.f, 0.f};

    // prologue: tile 0 into A0/B0
    lds_load16(pA0, smem + 0 + sd0);
    lds_load16(pA1, smem + 0 + sd1);
    lds_load16(pB0, smem + 8192 + sd0);
    lds_load16(pB1, smem + 8192 + sd1);
    pA0 += 32; pA1 += 32; pB0 += 32; pB1 += 32;

    for (int kt2 = 0; kt2 < 8; ++kt2) {
        PROJ_BODY(0, 8192, 16384, 24576, true)          // compute tile 2kt2 (buf0), stage 2kt2+1
        PROJ_BODY(16384, 24576, 0, 8192, (kt2 < 7))     // compute tile 2kt2+1 (buf1), stage 2kt2+2
    }

    float bvv[4];
#pragma unroll
    for (int nt = 0; nt < 4; ++nt) bvv[nt] = bias[n0 + wcol + nt * 16 + lm];

    // LDS epilogue with coalesced 16B stores for ALL outputs.
    __syncthreads();
    u16* epi = (u16*)smem;
    if (pj < 2) {
        u16* dst = (pj == 0) ? Qo : Ko;
#pragma unroll
        for (int mt = 0; mt < 4; ++mt)
#pragma unroll
            for (int nt = 0; nt < 4; ++nt) {
                int colL = wcol + nt * 16 + lm;
                int row0 = wrow + mt * 16 + lq * 4;
                u16x4 tv;
#pragma unroll
                for (int r = 0; r < 4; ++r) tv[r] = f2bf((acc[mt][nt][r] + bvv[nt]) * scale);
                int pu = (row0 >> 2) ^ ((colL >> 3) & 7);
                *(u16x4*)(epi + colL * 136 + pu * 4) = tv;
            }
        __syncthreads();
#pragma unroll
        for (int p = 0; p < 8; ++p) {
            int id = p * 256 + tid;
            int rr = id >> 4, ch = id & 15;
            int ur = rr >> 2, wr = rr & 3;
            u16x8 vv;
#pragma unroll
            for (int j = 0; j < 8; ++j) {
                int col = ch * 8 + j;            // col>>3 == ch
                vv[j] = epi[col * 136 + ((ur ^ (ch & 7)) * 4 + wr)];
            }
            *(u16x8*)(dst + ((size_t)b * L_SEQ + m0 + rr) * DM + n0 + ch * 8) = vv;
        }
    } else {
#pragma unroll
        for (int mt = 0; mt < 4; ++mt)
#pragma unroll
            for (int nt = 0; nt < 4; ++nt) {
                int colL = wcol + nt * 16 + lm;
                int row0 = wrow + mt * 16 + lq * 4;
                u16x4 tv;
#pragma unroll
                for (int r = 0; r < 4; ++r) tv[r] = f2bf(acc[mt][nt][r] + bvv[nt]);
                *(u16x4*)(epi + colL * 136 + row0) = tv;
            }
        __syncthreads();
#pragma unroll
        for (int p = 0; p < 8; ++p) {
            int id = p * 256 + tid;
            int rr = id >> 4, ch = id & 15;
            u16x8 vv = *(const u16x8*)(epi + rr * 136 + ch * 8);
            *(u16x8*)(Vto + ((size_t)b * DM + n0 + rr) * L_SEQ + m0 + ch * 8) = vv;
        }
    }
}

// ---------------- flash attention: 128-row pair per barrier (final, R10 config) ----------------
// Terminal configuration. Ledger: permlane32 P-exchange (R2, +3.3us), zero-conflict
// wide-period swizzle (R8, conflicts 4.26M->0, latency-hidden), l-sum via MFMA ones
// (R9, pipe rebalance), 16 barriers via 128-row pairs (R10, +2.0us). Measured nulls:
// counted-vmcnt ring (R3), occupancy reshapes (R4/R6), wave stagger (R12). Spill trap:
// any second live f32x16 or body duplication at 4 waves/EU (R5/R11). Issue budget:
// MfmaUtil+VALUBusy ~78% of the SHARED SIMD issue port; residual ~22% is barrier join
// + waitcnt with no ready wave — recoverable only by a ground-up co-designed schedule.
#define ATTN_SUB(KB, VB)                                                        \
    {                                                                           \
        bf16x8 af0 = *(const bf16x8*)(smem + (KB) + koffb[0]);                  \
        f32x16 s = __builtin_amdgcn_mfma_f32_32x32x16_bf16(af0, qf[0], z16,     \
                                                           0, 0, 0);            \
        _Pragma("unroll")                                                       \
        for (int c = 1; c < 4; ++c) {                                           \
            bf16x8 af = *(const bf16x8*)(smem + (KB) + koffb[c]);               \
            s = __builtin_amdgcn_mfma_f32_32x32x16_bf16(af, qf[c], s, 0, 0, 0); \
        }                                                                       \
        uint2 pw[4];                                                            \
        _Pragma("unroll")                                                       \
        for (int g2 = 0; g2 < 4; ++g2) {                                        \
            float p0 = __builtin_amdgcn_exp2f(s[4 * g2 + 0]);                   \
            float p1 = __builtin_amdgcn_exp2f(s[4 * g2 + 1]);                   \
            float p2 = __builtin_amdgcn_exp2f(s[4 * g2 + 2]);                   \
            float p3 = __builtin_amdgcn_exp2f(s[4 * g2 + 3]);                   \
            pw[g2].x = pk_bf16(p0, p1);                                         \
            pw[g2].y = pk_bf16(p2, p3);                                         \
        }                                                                       \
        _Pragma("unroll")                                                       \
        for (int c2 = 0; c2 < 2; ++c2) {                                        \
            uint2 pa = pw[2 * c2], pb = pw[2 * c2 + 1];                         \
            u32x2 rx = __builtin_amdgcn_permlane32_swap(pa.x, pb.x, false, false); \
            u32x2 ry = __builtin_amdgcn_permlane32_swap(pa.y, pb.y, false, false); \
            uint4 pu;                                                           \
            pu.x = rx[0]; pu.y = ry[0]; pu.z = rx[1]; pu.w = ry[1];             \
            bf16x8 pf;                                                          \
            __builtin_memcpy(&pf, &pu, 16);                                     \
            l_acc = __builtin_amdgcn_mfma_f32_32x32x16_bf16(pf, ones8, l_acc,   \
                                                            0, 0, 0);           \
            _Pragma("unroll")                                                   \
            for (int dt = 0; dt < 2; ++dt) {                                    \
                bf16x8 vf = *(const bf16x8*)(smem + (VB) + voffb[c2 * 2 + dt]); \
                o_acc[dt] = __builtin_amdgcn_mfma_f32_32x32x16_bf16(            \
                    pf, vf, o_acc[dt], 0, 0, 0);                                \
            }                                                                   \
        }                                                                       \
    }

#define ATTN_PAIR(KB, VB, NKB, NVB, DO_STAGE)                                   \
    {                                                                           \
        __syncthreads();                                                        \
        if (DO_STAGE) {                                                         \
            lds_load16(pKa, smem + (NKB) + sdb);                                \
            lds_load16(pKb, smem + (NKB) + 8192 + sdb);                         \
            lds_load16(pVa, smem + (NVB) + sdb);                                \
            lds_load16(pVb, smem + (NVB) + 8192 + sdb);                         \
            pKa += 128 * DM; pKb += 128 * DM; pVa += 128; pVb += 128;           \
        }                                                                       \
        ATTN_SUB(KB, VB)                                                        \
        ATTN_SUB((KB) + 8192, (VB) + 8192)                                      \
    }

__launch_bounds__(512, 4)
__global__ void attn(const u16* __restrict__ Q, const u16* __restrict__ K,
                     const u16* __restrict__ Vt, float* __restrict__ out) {
    __shared__ __align__(16) char smem[65536];
    // pair0: K @0 (a@0,b@8192), V @32768 (a,b@+8192); pair1: K @16384, V @49152
    // Q staged through K-pair0 (16KB); epilogue overlay: o_lds @0 (33.8KB), l @33792
    float* l_lds = (float*)(smem + 33792);
    float* o_lds = (float*)smem;

    const int i = blockIdx.x;
    const int g = i & 7, r_ = i >> 3;
    const int qb = r_ & 15, bh = ((r_ >> 4) << 3) + g;
    const int h_ = bh >> 2, b = bh & 3;

    const int tid = threadIdx.x, w = tid >> 6, lane = tid & 63;
    const int q0 = qb * 128;
    const int lm32 = lane & 31, hi = lane >> 5;
    const int qg = w & 3, hk = w >> 2;
    const int qrow = qg * 32 + lm32;

    const u16* Qb = Q + ((size_t)b * L_SEQ + q0) * DM + h_ * 64;
    const u16* Kb = K + (size_t)b * L_SEQ * DM + h_ * 64;
    const u16* Vb = Vt + ((size_t)b * DM + h_ * 64) * L_SEQ;

    // staging sources (1 slot of 16B per thread per buffer) + LDS dest byte offset
    const u16 *pKa, *pKb, *pVa, *pVb;
    const int sdb = w * 1024;   // (w*64)*16 bytes, wave-uniform
    {
        int r = tid >> 3, cc = (tid & 7) ^ swz(r);
        pKa = Kb + (size_t)r * DM + cc * 8;
        pKb = pKa + (size_t)64 * DM;          // rows 64-127 of the pair
        pVa = Vb + (size_t)r * L_SEQ + cc * 8;
        pVb = pVa + 64;                       // k-cols 64-127 of the pair
    }

    // loop-invariant fragment byte offsets (sub-b adds +8192 at use site)
    const int rk = hk * 32 + lm32;
    int koffb[4], voffb[4];
#pragma unroll
    for (int c = 0; c < 4; ++c)
        koffb[c] = rk * 128 + ((2 * c + hi) ^ swz(rk)) * 16;
#pragma unroll
    for (int c2 = 0; c2 < 2; ++c2)
#pragma unroll
        for (int dt = 0; dt < 2; ++dt) {
            int d = dt * 32 + lm32;
            int kc = hk * 4 + c2 * 2 + hi;
            voffb[c2 * 2 + dt] = d * 128 + (kc ^ swz(d)) * 16;
        }

    // stage Q (128x64 = 16KB) through K-pair0 buffers
#pragma unroll
    for (int j = 0; j < 2; ++j) {
        int s = j * 512 + tid;
        int r = s >> 3, cc = (s & 7) ^ swz(r);
        lds_load16(Qb + (size_t)r * DM + cc * 8, smem + j * 8192 + sdb);
    }
    __syncthreads();
    bf16x8 qf[4];
#pragma unroll
    for (int c = 0; c < 4; ++c) {
        int slot = (2 * c + hi) ^ swz(qrow);
        qf[c] = *(const bf16x8*)(smem + qrow * 128 + slot * 16);
    }
    __syncthreads();   // Q reads done; K bufs reusable

    const f32x16 z16 = zero16();   // persistent zero C-operand for QK^T
    f32x16 o_acc[2];
    o_acc[0] = zero16(); o_acc[1] = zero16();
    f32x16 l_acc = zero16();       // row-sum accumulator (l via MFMA)
    bf16x8 ones8;
    {
        u16 one = 0x3F80;          // bf16 1.0
#pragma unroll
        for (int j = 0; j < 8; ++j) ((u16*)&ones8)[j] = one;
    }

    // prologue: stage pair 0 into K@0 / V@32768
    lds_load16(pKa, smem + 0 + sdb);
    lds_load16(pKb, smem + 8192 + sdb);
    lds_load16(pVa, smem + 32768 + sdb);
    lds_load16(pVb, smem + 40960 + sdb);
    pKa += 128 * DM; pKb += 128 * DM; pVa += 128; pVb += 128;

    for (int kt2 = 0; kt2 < 8; ++kt2) {
        ATTN_PAIR(0,     32768, 16384, 49152, true)        // pair 2k, stage pair 2k+1
        ATTN_PAIR(16384, 49152, 0,     32768, (kt2 < 7))   // pair 2k+1, stage pair 2k+2
    }

    __syncthreads();   // kv bufs dead; overlay o_lds
    // l: per lane l_acc[4*g2+r] = l[q = r + 8*g2 + 4*hi] (col-independent).
    if (lm32 == 0) {
#pragma unroll
        for (int g2 = 0; g2 < 4; ++g2)
#pragma unroll
            for (int r = 0; r < 4; ++r)
                l_lds[hk * 128 + qg * 32 + r + 8 * g2 + 4 * hi] = l_acc[4 * g2 + r];
    }
    if (hk == 0) {
#pragma unroll
        for (int dt = 0; dt < 2; ++dt) {
            int d = dt * 32 + lm32;
#pragma unroll
            for (int g2 = 0; g2 < 4; ++g2) {
                f32x4 vq;
#pragma unroll
                for (int r = 0; r < 4; ++r) vq[r] = o_acc[dt][4 * g2 + r];
                *(f32x4*)(o_lds + d * 132 + qg * 32 + 8 * g2 + 4 * hi) = vq;
            }
        }
    }
    __syncthreads();
    if (hk == 1) {
#pragma unroll
        for (int dt = 0; dt < 2; ++dt) {
            int d = dt * 32 + lm32;
#pragma unroll
            for (int g2 = 0; g2 < 4; ++g2) {
                float* ad = o_lds + d * 132 + qg * 32 + 8 * g2 + 4 * hi;
                f32x4 cur = *(f32x4*)ad;
#pragma unroll
                for (int r = 0; r < 4; ++r) cur[r] += o_acc[dt][4 * g2 + r];
                *(f32x4*)ad = cur;
            }
        }
    }
    __syncthreads();
    float* ob = out + ((size_t)b * DM + h_ * 64) * L_SEQ + q0;
#pragma unroll
    for (int p = 0; p < 4; ++p) {
        int id = p * 512 + tid;
        int d = id >> 5, rc = id & 31;
        f32x4 vv = *(const f32x4*)(o_lds + d * 132 + rc * 4);
        f32x4 la = *(const f32x4*)(l_lds + rc * 4);
        f32x4 lb = *(const f32x4*)(l_lds + 128 + rc * 4);
#pragma unroll
        for (int j = 0; j < 4; ++j) vv[j] *= 1.0f / (la[j] + lb[j]);
        *(f32x4*)(ob + (size_t)d * L_SEQ + rc * 4) = vv;
    }
}

extern "C" void kernel_launch(void* const* d_in, const int* in_sizes, int n_in,
                              void* d_out, int out_size, void* d_ws, size_t ws_size,
                              hipStream_t stream) {
    const float* x1 = (const float*)d_in[0];
    const float* x2 = (const float*)d_in[1];
    const float* Wq = (const float*)d_in[2];
    const float* bq = (const float*)d_in[3];
    const float* Wk = (const float*)d_in[4];
    const float* bk = (const float*)d_in[5];
    const float* Wv = (const float*)d_in[6];
    const float* bv = (const float*)d_in[7];
    float* out = (float*)d_out;

    char* ws = (char*)d_ws;
    u16* x1T = (u16*)(ws);
    u16* x2T = (u16*)(ws + 8388608);
    u16* Wall = (u16*)(ws + 16777216);
    u16* Qb  = (u16*)(ws + 18350080);
    u16* Kb  = (u16*)(ws + 26738688);
    u16* Vtb = (u16*)(ws + 35127296);

    prep<<<dim3(16, 4, 9), 256, 0, stream>>>(x1, x2, Wq, Wk, Wv, x1T, Wall);
    proj_gemm<<<dim3(64, 12), 256, 0, stream>>>(x1T, x2T, Wall, bq, bk, bv, Qb, Kb, Vtb);
    attn<<<512, 512, 0, stream>>>(Qb, Kb, Vtb, out);
}